// Round 1
// baseline (34914.697 us; speedup 1.0000x reference)
//
#include <hip/hip_runtime.h>

typedef __attribute__((ext_vector_type(8))) short short8;       // bf16x8 MFMA frag
typedef __attribute__((ext_vector_type(8))) unsigned short ushort8;
typedef __attribute__((ext_vector_type(4))) float f32x4;

#define T_STEPS 2048

__device__ __forceinline__ unsigned short f2bf(float f) {
  unsigned u = __builtin_bit_cast(unsigned, f);
  unsigned r = u + 0x7fffu + ((u >> 16) & 1u);   // RNE
  return (unsigned short)(r >> 16);
}
__device__ __forceinline__ float bf2f(unsigned short h) {
  unsigned u = ((unsigned)h) << 16;
  return __builtin_bit_cast(float, u);
}
__device__ __forceinline__ float sigmoidf_(float v) {
  return 1.0f / (1.0f + __expf(-v));
}

// Pack layout for W (both Wx and Wh, each (512 x 2048) row-major):
// p[s][g][kt][l][e] : s<32 (hidden slice), g<4 (gate), kt<16 (K-tile), l<64 (lane), e<8
// element = W[k][c] with k = kt*32 + (l>>4)*8 + e ; c = g*512 + s*16 + (l&15)
// => B-fragment for mfma_f32_16x16x32_bf16 is a contiguous 16B run per lane.
__global__ void prep_kernel(const float* __restrict__ Wx, const float* __restrict__ Wh,
                            const float* __restrict__ h0,
                            unsigned short* __restrict__ wxp, unsigned short* __restrict__ whp,
                            unsigned short* __restrict__ hbuf, int* __restrict__ bar) {
  int idx = blockIdx.x * 256 + threadIdx.x;
  if (idx == 0) *bar = 0;
  if (idx < 2097152) {
    int which = idx >> 20;
    int r = idx & 1048575;
    int e = r & 7;
    int l = (r >> 3) & 63;
    int kt = (r >> 9) & 15;
    int g = (r >> 13) & 3;
    int s = r >> 15;
    int k = kt * 32 + ((l >> 4) << 3) + e;
    int c = g * 512 + s * 16 + (l & 15);
    const float* W = which ? Wh : Wx;
    unsigned short* dst = which ? whp : wxp;
    dst[r] = f2bf(W[k * 2048 + c]);
  } else if (idx < 2097152 + 16384) {
    int r = idx - 2097152;               // b*512 + k
    float v = h0[r];
    unsigned short hi = f2bf(v);
    unsigned short lo = f2bf(v - bf2f(hi));
    // h ring buffer: [buf][plane][32*512] bf16 ; step 0 reads buf 1
    hbuf[32768 + r] = hi;
    hbuf[49152 + r] = lo;
  }
}

__global__ void xprep_kernel(const float* __restrict__ x, unsigned short* __restrict__ xb) {
  size_t i8 = ((size_t)blockIdx.x * 256 + threadIdx.x) * 8;
  f32x4 a = *(const f32x4*)(x + i8);
  f32x4 b = *(const f32x4*)(x + i8 + 4);
  ushort8 o;
#pragma unroll
  for (int e = 0; e < 4; ++e) {
    o[e] = f2bf(a[e]);
    o[e + 4] = f2bf(b[e]);
  }
  *(ushort8*)(xb + i8) = o;
}

// 32 WGs x 256 threads (4 waves). WG s owns hidden units [16s, 16s+16) for all 32 batches.
// Wave g computes gate g (16 columns) for both 16-row M-tiles via MFMA 16x16x32 bf16.
// Gates meet in LDS; c-state lives in registers; h broadcast via global bf16 hi/lo planes.
// Grid-wide sync: monotonic atomic counter barrier (32 WGs <= 256 CUs => co-resident).
__global__ __launch_bounds__(256) void scan_kernel(
    const unsigned short* __restrict__ xb, const float* __restrict__ bias,
    const unsigned short* __restrict__ wxp, const unsigned short* __restrict__ whp,
    unsigned short* __restrict__ hbuf, float* __restrict__ out, int* __restrict__ bar) {
  __shared__ unsigned short WxL[4][16][512];   // 64 KB  [g][kt][l*8+e]
  __shared__ unsigned short WhL[4][16][512];   // 64 KB
  __shared__ float gbuf[4][32][16];            // 8 KB   [gate][batch][unit]

  const int s = blockIdx.x;
  const int tid = threadIdx.x;
  const int lane = tid & 63;
  const int gw = tid >> 6;                     // wave id == gate id

  // stage packed W slices into LDS (each slice is 32768 contiguous ushorts)
  {
    const ushort8* sx = (const ushort8*)(wxp + (size_t)s * 32768);
    const ushort8* sh = (const ushort8*)(whp + (size_t)s * 32768);
    ushort8* dx = (ushort8*)&WxL[0][0][0];
    ushort8* dh = (ushort8*)&WhL[0][0][0];
    for (int i = tid; i < 4096; i += 256) {
      dx[i] = sx[i];
      dh[i] = sh[i];
    }
  }

  const float breg = bias[gw * 512 + s * 16 + (lane & 15)];

  // c/h ownership: thread owns pairs p0=2*tid, p0+1  (p = batch*16 + unit)
  float c0 = 0.f, c1 = 0.f;
  const int p0 = tid * 2;
  const int ob = p0 >> 4;        // batch 0..31
  const int oj = p0 & 15;        // even unit index

  const int arow = lane & 15;    // A-frag row within M-tile
  const int kgrp = (lane >> 4) * 8;

  __syncthreads();

  for (int t = 0; t < T_STEPS; ++t) {
    f32x4 acc0 = {0.f, 0.f, 0.f, 0.f};
    f32x4 acc1 = {0.f, 0.f, 0.f, 0.f};
    const unsigned short* hrd = hbuf + ((t + 1) & 1) * 32768;
    const unsigned short* xt = xb + (size_t)t * 512;

#pragma unroll
    for (int kt = 0; kt < 16; ++kt) {
      const int k0 = kt * 32 + kgrp;
      short8 bx = *(const short8*)&WxL[gw][kt][lane * 8];
      short8 bh = *(const short8*)&WhL[gw][kt][lane * 8];
      // ---- M-tile 0 (batches 0..15)
      {
        short8 xf = *(const short8*)&xt[(size_t)arow * (2048 * 512) + k0];
        short8 hhi = *(const short8*)&hrd[(size_t)arow * 512 + k0];
        short8 hlo = *(const short8*)&hrd[16384 + (size_t)arow * 512 + k0];
        acc0 = __builtin_amdgcn_mfma_f32_16x16x32_bf16(xf, bx, acc0, 0, 0, 0);
        acc0 = __builtin_amdgcn_mfma_f32_16x16x32_bf16(hhi, bh, acc0, 0, 0, 0);
        acc0 = __builtin_amdgcn_mfma_f32_16x16x32_bf16(hlo, bh, acc0, 0, 0, 0);
      }
      // ---- M-tile 1 (batches 16..31)
      {
        short8 xf = *(const short8*)&xt[(size_t)(arow + 16) * (2048 * 512) + k0];
        short8 hhi = *(const short8*)&hrd[(size_t)(arow + 16) * 512 + k0];
        short8 hlo = *(const short8*)&hrd[16384 + (size_t)(arow + 16) * 512 + k0];
        acc1 = __builtin_amdgcn_mfma_f32_16x16x32_bf16(xf, bx, acc1, 0, 0, 0);
        acc1 = __builtin_amdgcn_mfma_f32_16x16x32_bf16(hhi, bh, acc1, 0, 0, 0);
        acc1 = __builtin_amdgcn_mfma_f32_16x16x32_bf16(hlo, bh, acc1, 0, 0, 0);
      }
    }

    // D layout: col = lane&15 (unit), row = (lane>>4)*4 + r (batch within tile)
#pragma unroll
    for (int r = 0; r < 4; ++r) {
      gbuf[gw][(lane >> 4) * 4 + r][lane & 15] = acc0[r] + breg;
      gbuf[gw][16 + (lane >> 4) * 4 + r][lane & 15] = acc1[r] + breg;
    }
    __syncthreads();

    // c/h update (2 (batch,unit) pairs per thread), gates: 0=i,1=f,2=o,3=g
    float2 vi = *(float2*)&gbuf[0][ob][oj];
    float2 vf = *(float2*)&gbuf[1][ob][oj];
    float2 vo = *(float2*)&gbuf[2][ob][oj];
    float2 vg = *(float2*)&gbuf[3][ob][oj];

    float i0 = sigmoidf_(vi.x), f0 = sigmoidf_(vf.x), o0 = sigmoidf_(vo.x), g0 = tanhf(vg.x);
    float i1 = sigmoidf_(vi.y), f1 = sigmoidf_(vf.y), o1 = sigmoidf_(vo.y), g1 = tanhf(vg.y);
    c0 = f0 * c0 + i0 * g0;
    c1 = f1 * c1 + i1 * g1;
    float hv0 = o0 * tanhf(c0);
    float hv1 = o1 * tanhf(c1);

    // fp32 output
    float2 hv = {hv0, hv1};
    *(float2*)&out[(size_t)ob * (2048 * 512) + (size_t)t * 512 + s * 16 + oj] = hv;

    // bf16 hi/lo h for the next step's broadcast
    unsigned short hi0 = f2bf(hv0), hi1 = f2bf(hv1);
    unsigned short lo0 = f2bf(hv0 - bf2f(hi0)), lo1 = f2bf(hv1 - bf2f(hi1));
    unsigned short* hwr = hbuf + (t & 1) * 32768;
    ushort2 whi = {hi0, hi1}, wlo = {lo0, lo1};
    *(ushort2*)&hwr[ob * 512 + s * 16 + oj] = whi;
    *(ushort2*)&hwr[16384 + ob * 512 + s * 16 + oj] = wlo;

    // grid barrier (monotonic counter; release h writes, acquire others')
    if (t < T_STEPS - 1) {
      __threadfence();
      __syncthreads();
      if (tid == 0) {
        __hip_atomic_fetch_add(bar, 1, __ATOMIC_RELEASE, __HIP_MEMORY_SCOPE_AGENT);
        const int target = 32 * (t + 1);
        while (__hip_atomic_load(bar, __ATOMIC_ACQUIRE, __HIP_MEMORY_SCOPE_AGENT) < target) {
          __builtin_amdgcn_s_sleep(2);
        }
        __threadfence();
      }
      __syncthreads();
    }
  }
}

extern "C" void kernel_launch(void* const* d_in, const int* in_sizes, int n_in,
                              void* d_out, int out_size, void* d_ws, size_t ws_size,
                              hipStream_t stream) {
  const float* x = (const float*)d_in[0];     // (32, 2048, 512) f32
  const float* h0 = (const float*)d_in[1];    // (32, 512) f32
  const float* Wx = (const float*)d_in[2];    // (512, 2048) f32
  const float* Wh = (const float*)d_in[3];    // (512, 2048) f32
  const float* bias = (const float*)d_in[4];  // (2048,) f32
  float* out = (float*)d_out;

  char* ws = (char*)d_ws;
  unsigned short* wxp = (unsigned short*)(ws);                            // 2 MB
  unsigned short* whp = (unsigned short*)(ws + (2u << 20));               // 2 MB
  unsigned short* hbuf = (unsigned short*)(ws + (4u << 20));              // 128 KB
  int* bar = (int*)(ws + (4u << 20) + (256u << 10));                      // 4 B
  unsigned short* xb = (unsigned short*)(ws + (8u << 20));                // 67 MB

  hipLaunchKernelGGL(prep_kernel, dim3(8256), dim3(256), 0, stream,
                     Wx, Wh, h0, wxp, whp, hbuf, bar);
  hipLaunchKernelGGL(xprep_kernel, dim3(16384), dim3(256), 0, stream, x, xb);
  hipLaunchKernelGGL(scan_kernel, dim3(32), dim3(256), 0, stream,
                     xb, bias, wxp, whp, hbuf, out, bar);
}

// Round 2
// 21494.446 us; speedup vs baseline: 1.6244x; 1.6244x over previous
//
#include <hip/hip_runtime.h>

typedef __attribute__((ext_vector_type(8))) short short8;       // bf16x8 MFMA frag
typedef __attribute__((ext_vector_type(8))) unsigned short ushort8;
typedef __attribute__((ext_vector_type(4))) float f32x4;

#define T_STEPS 2048
#define NWG 32

static __device__ __forceinline__ unsigned short f2bf(float f) {
  unsigned u = __builtin_bit_cast(unsigned, f);
  unsigned r = u + 0x7fffu + ((u >> 16) & 1u);   // RNE
  return (unsigned short)(r >> 16);
}
static __device__ __forceinline__ float bf2f(unsigned short h) {
  unsigned u = ((unsigned)h) << 16;
  return __builtin_bit_cast(float, u);
}
static __device__ __forceinline__ float sigmoidf_(float v) {
  return 1.0f / (1.0f + __expf(-v));
}

// Device-coherent 16B load as 4 relaxed agent-scope dword atomics (sc0 sc1:
// bypasses L1/L2, reads the coherence point — always fresh, no buffer_inv).
static __device__ __forceinline__ short8 ldh16(const unsigned short* p) {
  union { short8 v; unsigned u[4]; } r;
#pragma unroll
  for (int i = 0; i < 4; ++i)
    r.u[i] = __hip_atomic_load((const unsigned*)p + i, __ATOMIC_RELAXED,
                               __HIP_MEMORY_SCOPE_AGENT);
  return r.v;
}

// Pack layout for W (both Wx and Wh, each (512 x 2048) row-major):
// p[s][g][kt][l][e] : s<32 (hidden slice), g<4 (gate), kt<16 (K-tile), l<64, e<8
// element = W[k][c] with k = kt*32 + (l>>4)*8 + e ; c = g*512 + s*16 + (l&15)
__global__ void prep_kernel(const float* __restrict__ Wx, const float* __restrict__ Wh,
                            const float* __restrict__ h0,
                            unsigned short* __restrict__ wxp, unsigned short* __restrict__ whp,
                            unsigned short* __restrict__ hbuf, int* __restrict__ bar) {
  int idx = blockIdx.x * 256 + threadIdx.x;
  if (idx == 0)
    __hip_atomic_store(bar, 0, __ATOMIC_RELAXED, __HIP_MEMORY_SCOPE_AGENT);
  if (idx < 2097152) {
    int which = idx >> 20;
    int r = idx & 1048575;
    int e = r & 7;
    int l = (r >> 3) & 63;
    int kt = (r >> 9) & 15;
    int g = (r >> 13) & 3;
    int s = r >> 15;
    int k = kt * 32 + ((l >> 4) << 3) + e;
    int c = g * 512 + s * 16 + (l & 15);
    const float* W = which ? Wh : Wx;
    unsigned short* dst = which ? whp : wxp;
    dst[r] = f2bf(W[k * 2048 + c]);
  } else if (idx < 2097152 + 8192) {
    int r2 = (idx - 2097152) * 2;          // pair of (b*512+k)
    float v0 = h0[r2], v1 = h0[r2 + 1];
    unsigned short hi0 = f2bf(v0), hi1 = f2bf(v1);
    unsigned short lo0 = f2bf(v0 - bf2f(hi0)), lo1 = f2bf(v1 - bf2f(hi1));
    // h ring: [buf][plane][32*512] bf16 ; step 0 reads buf 1 (planes at 32768/49152)
    __hip_atomic_store((unsigned*)&hbuf[32768 + r2], (unsigned)hi0 | ((unsigned)hi1 << 16),
                       __ATOMIC_RELAXED, __HIP_MEMORY_SCOPE_AGENT);
    __hip_atomic_store((unsigned*)&hbuf[49152 + r2], (unsigned)lo0 | ((unsigned)lo1 << 16),
                       __ATOMIC_RELAXED, __HIP_MEMORY_SCOPE_AGENT);
  }
}

// Transpose x (b,t,d) f32 -> xt (t,b,d) bf16 so the scan reads one contiguous
// 32 KB block per step.
__global__ void xprep_kernel(const float* __restrict__ x, unsigned short* __restrict__ xb) {
  size_t i8 = ((size_t)blockIdx.x * 256 + threadIdx.x) * 8;
  int t = (int)(i8 >> 14);
  int r = (int)(i8 & 16383);
  int b = r >> 9;
  int d = r & 511;
  const float* src = x + ((size_t)b * 2048 + (size_t)t) * 512 + d;
  f32x4 a = *(const f32x4*)src;
  f32x4 c = *(const f32x4*)(src + 4);
  ushort8 o;
#pragma unroll
  for (int e = 0; e < 4; ++e) {
    o[e] = f2bf(a[e]);
    o[e + 4] = f2bf(c[e]);
  }
  *(ushort8*)(xb + i8) = o;
}

// 32 WGs x 256 threads. WG s owns units [16s,16s+16) for all 32 batches.
// Wave w owns K-slice [128w, 128w+128) and computes partial gate sums for all
// 4 gates x 2 M-tiles; partials meet in LDS (2-phase accumulate). h is
// exchanged via device-coherent relaxed atomics — no fences, no L2 flushes.
__global__ __launch_bounds__(256, 1) void scan_kernel(
    const unsigned short* __restrict__ xb, const float* __restrict__ bias,
    const unsigned short* __restrict__ wxp, const unsigned short* __restrict__ whp,
    unsigned short* __restrict__ hbuf, float* __restrict__ out, int* __restrict__ bar) {
  __shared__ unsigned short WxL[4][16][512];   // 64 KB  [g][ktglob][l*8+e]
  __shared__ unsigned short WhL[4][16][512];   // 64 KB
  __shared__ float gA[32][68];                 // 8.5 KB partial sums (padded)
  __shared__ float gB[32][68];                 // 8.5 KB

  const int s = blockIdx.x;
  const int tid = threadIdx.x;
  const int lane = tid & 63;
  const int gw = tid >> 6;                     // wave id == K-slice id

  {
    const ushort8* sx = (const ushort8*)(wxp + (size_t)s * 32768);
    const ushort8* sh = (const ushort8*)(whp + (size_t)s * 32768);
    ushort8* dx = (ushort8*)&WxL[0][0][0];
    ushort8* dh = (ushort8*)&WhL[0][0][0];
    for (int i = tid; i < 4096; i += 256) {
      dx[i] = sx[i];
      dh[i] = sh[i];
    }
  }

  // c/h ownership: thread owns pairs p0=2*tid, p0+1 (p = batch*16 + unit)
  const int p0 = tid * 2;
  const int ob = p0 >> 4;        // batch 0..31
  const int oj = p0 & 15;        // even unit index
  float2 bias2[4];
#pragma unroll
  for (int g = 0; g < 4; ++g)
    bias2[g] = *(const float2*)&bias[g * 512 + s * 16 + oj];

  float c0 = 0.f, c1 = 0.f;
  const int arow = lane & 15;
  const int kgrp = (lane >> 4) * 8;

  __syncthreads();

  for (int t = 0; t < T_STEPS; ++t) {
    f32x4 acc[4][2];
#pragma unroll
    for (int nt = 0; nt < 4; ++nt)
#pragma unroll
      for (int mt = 0; mt < 2; ++mt)
        acc[nt][mt] = (f32x4){0.f, 0.f, 0.f, 0.f};

    const unsigned short* hrd = hbuf + ((t + 1) & 1) * 32768;
    const unsigned short* xt = xb + (size_t)t * 16384;

#pragma unroll
    for (int kt = 0; kt < 4; ++kt) {
      const int k0 = (gw << 7) + (kt << 5) + kgrp;
      const int ktg = (gw << 2) + kt;
      short8 xf0 = *(const short8*)&xt[arow * 512 + k0];
      short8 xf1 = *(const short8*)&xt[(arow + 16) * 512 + k0];
      short8 hh0 = ldh16(&hrd[arow * 512 + k0]);
      short8 hl0 = ldh16(&hrd[16384 + arow * 512 + k0]);
      short8 hh1 = ldh16(&hrd[(arow + 16) * 512 + k0]);
      short8 hl1 = ldh16(&hrd[16384 + (arow + 16) * 512 + k0]);
#pragma unroll
      for (int nt = 0; nt < 4; ++nt) {
        short8 bx = *(const short8*)&WxL[nt][ktg][lane * 8];
        short8 bh = *(const short8*)&WhL[nt][ktg][lane * 8];
        acc[nt][0] = __builtin_amdgcn_mfma_f32_16x16x32_bf16(xf0, bx, acc[nt][0], 0, 0, 0);
        acc[nt][0] = __builtin_amdgcn_mfma_f32_16x16x32_bf16(hh0, bh, acc[nt][0], 0, 0, 0);
        acc[nt][0] = __builtin_amdgcn_mfma_f32_16x16x32_bf16(hl0, bh, acc[nt][0], 0, 0, 0);
        acc[nt][1] = __builtin_amdgcn_mfma_f32_16x16x32_bf16(xf1, bx, acc[nt][1], 0, 0, 0);
        acc[nt][1] = __builtin_amdgcn_mfma_f32_16x16x32_bf16(hh1, bh, acc[nt][1], 0, 0, 0);
        acc[nt][1] = __builtin_amdgcn_mfma_f32_16x16x32_bf16(hl1, bh, acc[nt][1], 0, 0, 0);
      }
    }

    // 2-phase partial-sum exchange: waves 2,3 store; waves 0,1 accumulate.
    {
      float* dst = (gw & 1) ? &gB[0][0] : &gA[0][0];
      if (gw >= 2) {
#pragma unroll
        for (int nt = 0; nt < 4; ++nt)
#pragma unroll
          for (int mt = 0; mt < 2; ++mt)
#pragma unroll
            for (int r = 0; r < 4; ++r)
              dst[(mt * 16 + (lane >> 4) * 4 + r) * 68 + nt * 16 + (lane & 15)] =
                  acc[nt][mt][r];
      }
      __syncthreads();
      if (gw < 2) {
#pragma unroll
        for (int nt = 0; nt < 4; ++nt)
#pragma unroll
          for (int mt = 0; mt < 2; ++mt)
#pragma unroll
            for (int r = 0; r < 4; ++r)
              dst[(mt * 16 + (lane >> 4) * 4 + r) * 68 + nt * 16 + (lane & 15)] +=
                  acc[nt][mt][r];
      }
      __syncthreads();
    }

    // gate update for this thread's 2 (batch,unit) pairs
    float2 v4[4];
#pragma unroll
    for (int g = 0; g < 4; ++g) {
      float2 a2 = *(float2*)&gA[ob][g * 16 + oj];
      float2 b2 = *(float2*)&gB[ob][g * 16 + oj];
      v4[g].x = a2.x + b2.x + bias2[g].x;
      v4[g].y = a2.y + b2.y + bias2[g].y;
    }
    float i0 = sigmoidf_(v4[0].x), i1 = sigmoidf_(v4[0].y);
    float f0 = sigmoidf_(v4[1].x), f1 = sigmoidf_(v4[1].y);
    float o0 = sigmoidf_(v4[2].x), o1 = sigmoidf_(v4[2].y);
    float g0 = tanhf(v4[3].x), g1 = tanhf(v4[3].y);
    c0 = f0 * c0 + i0 * g0;
    c1 = f1 * c1 + i1 * g1;
    float hv0 = o0 * tanhf(c0);
    float hv1 = o1 * tanhf(c1);

    // publish h (hi/lo bf16) via relaxed agent atomics (write-through to IF$)
    unsigned short hi0 = f2bf(hv0), hi1 = f2bf(hv1);
    unsigned short lo0 = f2bf(hv0 - bf2f(hi0)), lo1 = f2bf(hv1 - bf2f(hi1));
    unsigned short* hwr = hbuf + (t & 1) * 32768;
    const int hidx = ob * 512 + s * 16 + oj;
    __hip_atomic_store((unsigned*)&hwr[hidx], (unsigned)hi0 | ((unsigned)hi1 << 16),
                       __ATOMIC_RELAXED, __HIP_MEMORY_SCOPE_AGENT);
    __hip_atomic_store((unsigned*)&hwr[16384 + hidx], (unsigned)lo0 | ((unsigned)lo1 << 16),
                       __ATOMIC_RELAXED, __HIP_MEMORY_SCOPE_AGENT);

    float2 hv2 = {hv0, hv1};
    float* outp = &out[(size_t)ob * (2048 * 512) + (size_t)t * 512 + s * 16 + oj];

    if (t < T_STEPS - 1) {
      __syncthreads();   // drains vmcnt -> all h stores visible at coherence point
      if (tid == 0)
        __hip_atomic_fetch_add(bar, 1, __ATOMIC_RELAXED, __HIP_MEMORY_SCOPE_AGENT);
      *(float2*)outp = hv2;          // overlapped with the poll
      if (tid == 0) {
        const int target = NWG * (t + 1);
        while (__hip_atomic_load(bar, __ATOMIC_RELAXED, __HIP_MEMORY_SCOPE_AGENT) < target)
          __builtin_amdgcn_s_sleep(1);
      }
      __syncthreads();
    } else {
      *(float2*)outp = hv2;
    }
  }
}

extern "C" void kernel_launch(void* const* d_in, const int* in_sizes, int n_in,
                              void* d_out, int out_size, void* d_ws, size_t ws_size,
                              hipStream_t stream) {
  const float* x = (const float*)d_in[0];     // (32, 2048, 512) f32
  const float* h0 = (const float*)d_in[1];    // (32, 512) f32
  const float* Wx = (const float*)d_in[2];    // (512, 2048) f32
  const float* Wh = (const float*)d_in[3];    // (512, 2048) f32
  const float* bias = (const float*)d_in[4];  // (2048,) f32
  float* out = (float*)d_out;

  char* ws = (char*)d_ws;
  unsigned short* wxp = (unsigned short*)(ws);                            // 2 MB
  unsigned short* whp = (unsigned short*)(ws + (2u << 20));               // 2 MB
  unsigned short* hbuf = (unsigned short*)(ws + (4u << 20));              // 128 KB
  int* bar = (int*)(ws + (4u << 20) + (256u << 10));                      // 4 B
  unsigned short* xb = (unsigned short*)(ws + (8u << 20));                // 67 MB

  hipLaunchKernelGGL(prep_kernel, dim3(8256), dim3(256), 0, stream,
                     Wx, Wh, h0, wxp, whp, hbuf, bar);
  hipLaunchKernelGGL(xprep_kernel, dim3(16384), dim3(256), 0, stream, x, xb);
  hipLaunchKernelGGL(scan_kernel, dim3(NWG), dim3(256), 0, stream,
                     xb, bias, wxp, whp, hbuf, out, bar);
}

// Round 3
// 14027.892 us; speedup vs baseline: 2.4889x; 1.5323x over previous
//
#include <hip/hip_runtime.h>

typedef __attribute__((ext_vector_type(8))) short short8;       // bf16x8 MFMA frag
typedef __attribute__((ext_vector_type(8))) unsigned short ushort8;
typedef __attribute__((ext_vector_type(4))) float f32x4;

#define T_STEPS 2048
#define NWG 32

static __device__ __forceinline__ unsigned short f2bf(float f) {
  unsigned u = __builtin_bit_cast(unsigned, f);
  unsigned r = u + 0x7fffu + ((u >> 16) & 1u);   // RNE
  return (unsigned short)(r >> 16);
}
static __device__ __forceinline__ float bf2f(unsigned short h) {
  unsigned u = ((unsigned)h) << 16;
  return __builtin_bit_cast(float, u);
}
static __device__ __forceinline__ float sigmoidf_(float v) {
  return 1.0f / (1.0f + __expf(-v));
}
static __device__ __forceinline__ unsigned long long ld64cc(const unsigned long long* p) {
  return __hip_atomic_load(p, __ATOMIC_RELAXED, __HIP_MEMORY_SCOPE_AGENT);
}

// Pack layout for W (both Wx and Wh, each (512 x 2048) row-major):
// p[s][g][kt][l][e] : s<32 (hidden slice), g<4 (gate), kt<16 (K-tile), l<64, e<8
// element = W[k][c] with k = kt*32 + (l>>4)*8 + e ; c = g*512 + s*16 + (l&15)
//
// h exchange protocol: hbuf[slot][plane][32*512] bf16, slot = step&1 for the
// h INPUT of that step. Every bf16 ushort carries tag=(step>>1)&3 in its 2
// mantissa LSBs (hi-plane steal is absorbed by lo = h - bf2f(hi_forced); only
// the lo-plane steal loses ~2^-14 |h|). Any read that sees all tags == tag(t)
// is guaranteed generation-t data (max producer/consumer skew < 2 steps; ring
// aliasing t vs t-2 differs by 1 mod 4; replay leftovers tag 3/0 and 0xAA
// poison tag 2 never collide with the first expected tags 0/1).
__global__ void prep_kernel(const float* __restrict__ Wx, const float* __restrict__ Wh,
                            const float* __restrict__ h0,
                            unsigned short* __restrict__ wxp, unsigned short* __restrict__ whp,
                            unsigned short* __restrict__ hbuf) {
  int idx = blockIdx.x * 256 + threadIdx.x;
  if (idx < 2097152) {
    int which = idx >> 20;
    int r = idx & 1048575;
    int e = r & 7;
    int l = (r >> 3) & 63;
    int kt = (r >> 9) & 15;
    int g = (r >> 13) & 3;
    int s = r >> 15;
    int k = kt * 32 + ((l >> 4) << 3) + e;
    int c = g * 512 + s * 16 + (l & 15);
    const float* W = which ? Wh : Wx;
    unsigned short* dst = which ? whp : wxp;
    dst[r] = f2bf(W[k * 2048 + c]);
  } else if (idx < 2097152 + 8192) {
    int r2 = (idx - 2097152) * 2;          // pair of (b*512+k)
    float v0 = h0[r2], v1 = h0[r2 + 1];
    // tag(step 0) = 0 : force 2 LSBs of hi and lo to 0
    unsigned short hi0 = f2bf(v0) & 0xFFFCu, hi1 = f2bf(v1) & 0xFFFCu;
    unsigned short lo0 = f2bf(v0 - bf2f(hi0)) & 0xFFFCu;
    unsigned short lo1 = f2bf(v1 - bf2f(hi1)) & 0xFFFCu;
    // slot 0 (input for step 0): planes at 0 / 16384
    __hip_atomic_store((unsigned*)&hbuf[r2], (unsigned)hi0 | ((unsigned)hi1 << 16),
                       __ATOMIC_RELAXED, __HIP_MEMORY_SCOPE_AGENT);
    __hip_atomic_store((unsigned*)&hbuf[16384 + r2], (unsigned)lo0 | ((unsigned)lo1 << 16),
                       __ATOMIC_RELAXED, __HIP_MEMORY_SCOPE_AGENT);
  }
}

// Transpose x (b,t,d) f32 -> xt (t,b,d) bf16 (one contiguous 32 KB block/step).
__global__ void xprep_kernel(const float* __restrict__ x, unsigned short* __restrict__ xb) {
  size_t i8 = ((size_t)blockIdx.x * 256 + threadIdx.x) * 8;
  int t = (int)(i8 >> 14);
  int r = (int)(i8 & 16383);
  int b = r >> 9;
  int d = r & 511;
  const float* src = x + ((size_t)b * 2048 + (size_t)t) * 512 + d;
  f32x4 a = *(const f32x4*)src;
  f32x4 c = *(const f32x4*)(src + 4);
  ushort8 o;
#pragma unroll
  for (int e = 0; e < 4; ++e) {
    o[e] = f2bf(a[e]);
    o[e + 4] = f2bf(c[e]);
  }
  *(ushort8*)(xb + i8) = o;
}

// 32 WGs x 256 threads. WG s owns units [16s,16s+16) for all 32 batches.
// Wave w owns K-slice [128w,128w+128) for all 4 gates x 2 M-tiles; partials
// meet in LDS. No grid barrier: consumers poll the tagged h data directly.
__global__ __launch_bounds__(256, 1) void scan_kernel(
    const unsigned short* __restrict__ xb, const float* __restrict__ bias,
    const unsigned short* __restrict__ wxp, const unsigned short* __restrict__ whp,
    unsigned short* __restrict__ hbuf, float* __restrict__ out) {
  __shared__ unsigned short WxL[4][16][512];   // 64 KB  [g][ktglob][l*8+e]
  __shared__ unsigned short WhL[4][16][512];   // 64 KB
  __shared__ float gA[32][68];                 // 8.5 KB partial sums (padded)
  __shared__ float gB[32][68];                 // 8.5 KB

  const int s = blockIdx.x;
  const int tid = threadIdx.x;
  const int lane = tid & 63;
  const int gw = tid >> 6;                     // wave id == K-slice id

  {
    const ushort8* sx = (const ushort8*)(wxp + (size_t)s * 32768);
    const ushort8* sh = (const ushort8*)(whp + (size_t)s * 32768);
    ushort8* dx = (ushort8*)&WxL[0][0][0];
    ushort8* dh = (ushort8*)&WhL[0][0][0];
    for (int i = tid; i < 4096; i += 256) {
      dx[i] = sx[i];
      dh[i] = sh[i];
    }
  }

  const int p0 = tid * 2;
  const int ob = p0 >> 4;        // batch 0..31 (wave-aligned: wave w -> batches 8w..8w+7)
  const int oj = p0 & 15;        // even unit index
  float2 bias2[4];
#pragma unroll
  for (int g = 0; g < 4; ++g)
    bias2[g] = *(const float2*)&bias[g * 512 + s * 16 + oj];

  float c0 = 0.f, c1 = 0.f;
  const int arow = lane & 15;
  const int kgrp = (lane >> 4) * 8;

  __syncthreads();

  // prologue: prefetch x A-frags for t=0
  short8 xf0[4], xf1[4];
#pragma unroll
  for (int kt = 0; kt < 4; ++kt) {
    const int k0 = (gw << 7) + (kt << 5) + kgrp;
    xf0[kt] = *(const short8*)&xb[arow * 512 + k0];
    xf1[kt] = *(const short8*)&xb[(arow + 16) * 512 + k0];
  }

  for (int t = 0; t < T_STEPS; ++t) {
    // ---- phase 1: poll tagged h (the polls ARE the data loads)
    const unsigned long long tagpat =
        0x0001000100010001ull * (unsigned long long)((t >> 1) & 3);
    const unsigned long long* hb64 =
        (const unsigned long long*)(hbuf + (t & 1) * 32768);
    unsigned long long v[32];
    for (;;) {
#pragma unroll
      for (int kt = 0; kt < 4; ++kt) {
        const int k0 = (gw << 7) + (kt << 5) + kgrp;
        const int b00 = (arow * 512 + k0) >> 2;
        const int b01 = (16384 + arow * 512 + k0) >> 2;
        const int b10 = ((arow + 16) * 512 + k0) >> 2;
        const int b11 = (16384 + (arow + 16) * 512 + k0) >> 2;
        v[kt * 8 + 0] = ld64cc(hb64 + b00);
        v[kt * 8 + 1] = ld64cc(hb64 + b00 + 1);
        v[kt * 8 + 2] = ld64cc(hb64 + b01);
        v[kt * 8 + 3] = ld64cc(hb64 + b01 + 1);
        v[kt * 8 + 4] = ld64cc(hb64 + b10);
        v[kt * 8 + 5] = ld64cc(hb64 + b10 + 1);
        v[kt * 8 + 6] = ld64cc(hb64 + b11);
        v[kt * 8 + 7] = ld64cc(hb64 + b11 + 1);
      }
      unsigned long long bad = 0;
#pragma unroll
      for (int i = 0; i < 32; ++i)
        bad |= (v[i] & 0x0003000300030003ull) ^ tagpat;
      if (__all(bad == 0)) break;
    }

    // ---- phase 2: MFMA (x frags prefetched last iter; W from LDS)
    f32x4 acc[4][2];
#pragma unroll
    for (int nt = 0; nt < 4; ++nt)
#pragma unroll
      for (int mt = 0; mt < 2; ++mt)
        acc[nt][mt] = (f32x4){0.f, 0.f, 0.f, 0.f};

#pragma unroll
    for (int kt = 0; kt < 4; ++kt) {
      const int ktg = (gw << 2) + kt;
      union { unsigned long long q[2]; short8 s8; } u0, u1, u2, u3;
      u0.q[0] = v[kt * 8 + 0]; u0.q[1] = v[kt * 8 + 1];   // hh0
      u1.q[0] = v[kt * 8 + 2]; u1.q[1] = v[kt * 8 + 3];   // hl0
      u2.q[0] = v[kt * 8 + 4]; u2.q[1] = v[kt * 8 + 5];   // hh1
      u3.q[0] = v[kt * 8 + 6]; u3.q[1] = v[kt * 8 + 7];   // hl1
#pragma unroll
      for (int nt = 0; nt < 4; ++nt) {
        short8 bx = *(const short8*)&WxL[nt][ktg][lane * 8];
        short8 bh = *(const short8*)&WhL[nt][ktg][lane * 8];
        acc[nt][0] = __builtin_amdgcn_mfma_f32_16x16x32_bf16(xf0[kt], bx, acc[nt][0], 0, 0, 0);
        acc[nt][0] = __builtin_amdgcn_mfma_f32_16x16x32_bf16(u0.s8, bh, acc[nt][0], 0, 0, 0);
        acc[nt][0] = __builtin_amdgcn_mfma_f32_16x16x32_bf16(u1.s8, bh, acc[nt][0], 0, 0, 0);
        acc[nt][1] = __builtin_amdgcn_mfma_f32_16x16x32_bf16(xf1[kt], bx, acc[nt][1], 0, 0, 0);
        acc[nt][1] = __builtin_amdgcn_mfma_f32_16x16x32_bf16(u2.s8, bh, acc[nt][1], 0, 0, 0);
        acc[nt][1] = __builtin_amdgcn_mfma_f32_16x16x32_bf16(u3.s8, bh, acc[nt][1], 0, 0, 0);
      }
    }

    // ---- phase 3: LDS partial-sum exchange (waves 2,3 store; 0,1 add)
    {
      float* dst = (gw & 1) ? &gB[0][0] : &gA[0][0];
      if (gw >= 2) {
#pragma unroll
        for (int nt = 0; nt < 4; ++nt)
#pragma unroll
          for (int mt = 0; mt < 2; ++mt)
#pragma unroll
            for (int r = 0; r < 4; ++r)
              dst[(mt * 16 + (lane >> 4) * 4 + r) * 68 + nt * 16 + (lane & 15)] =
                  acc[nt][mt][r];
      }
      __syncthreads();
      if (gw < 2) {
#pragma unroll
        for (int nt = 0; nt < 4; ++nt)
#pragma unroll
          for (int mt = 0; mt < 2; ++mt)
#pragma unroll
            for (int r = 0; r < 4; ++r)
              dst[(mt * 16 + (lane >> 4) * 4 + r) * 68 + nt * 16 + (lane & 15)] +=
                  acc[nt][mt][r];
      }
      __syncthreads();
    }

    // ---- phase 4: gates, c/h update
    float2 v4[4];
#pragma unroll
    for (int g = 0; g < 4; ++g) {
      float2 a2 = *(float2*)&gA[ob][g * 16 + oj];
      float2 b2 = *(float2*)&gB[ob][g * 16 + oj];
      v4[g].x = a2.x + b2.x + bias2[g].x;
      v4[g].y = a2.y + b2.y + bias2[g].y;
    }
    float i0 = sigmoidf_(v4[0].x), i1 = sigmoidf_(v4[0].y);
    float f0 = sigmoidf_(v4[1].x), f1 = sigmoidf_(v4[1].y);
    float o0 = sigmoidf_(v4[2].x), o1 = sigmoidf_(v4[2].y);
    float g0 = tanhf(v4[3].x), g1 = tanhf(v4[3].y);
    c0 = f0 * c0 + i0 * g0;
    c1 = f1 * c1 + i1 * g1;
    float hv0 = o0 * tanhf(c0);
    float hv1 = o1 * tanhf(c1);

    // ---- phase 5: publish tagged h ASAP (fire-and-forget, no ack, no flag)
    const unsigned ntag = (unsigned)(((t + 1) >> 1) & 3);
    unsigned short hi0 = (unsigned short)((f2bf(hv0) & 0xFFFCu) | ntag);
    unsigned short hi1 = (unsigned short)((f2bf(hv1) & 0xFFFCu) | ntag);
    unsigned short lo0 = (unsigned short)((f2bf(hv0 - bf2f(hi0)) & 0xFFFCu) | ntag);
    unsigned short lo1 = (unsigned short)((f2bf(hv1 - bf2f(hi1)) & 0xFFFCu) | ntag);
    unsigned short* hwr = hbuf + ((t + 1) & 1) * 32768;
    const int hidx = ob * 512 + s * 16 + oj;
    __hip_atomic_store((unsigned*)&hwr[hidx], (unsigned)hi0 | ((unsigned)hi1 << 16),
                       __ATOMIC_RELAXED, __HIP_MEMORY_SCOPE_AGENT);
    __hip_atomic_store((unsigned*)&hwr[16384 + hidx], (unsigned)lo0 | ((unsigned)lo1 << 16),
                       __ATOMIC_RELAXED, __HIP_MEMORY_SCOPE_AGENT);

    // fp32 output (plain store, off critical path)
    float2 hv2 = {hv0, hv1};
    *(float2*)&out[(size_t)ob * (2048 * 512) + (size_t)t * 512 + s * 16 + oj] = hv2;

    // ---- phase 6: prefetch next step's x A-frags into the poll shadow
    {
      const int tn = (t + 1 < T_STEPS) ? (t + 1) : t;
      const unsigned short* xt1 = xb + (size_t)tn * 16384;
#pragma unroll
      for (int kt = 0; kt < 4; ++kt) {
        const int k0 = (gw << 7) + (kt << 5) + kgrp;
        xf0[kt] = *(const short8*)&xt1[arow * 512 + k0];
        xf1[kt] = *(const short8*)&xt1[(arow + 16) * 512 + k0];
      }
    }

    // gbuf reuse guard: next step's gbuf writes must not pass this step's reads
    __syncthreads();
  }
}

extern "C" void kernel_launch(void* const* d_in, const int* in_sizes, int n_in,
                              void* d_out, int out_size, void* d_ws, size_t ws_size,
                              hipStream_t stream) {
  const float* x = (const float*)d_in[0];     // (32, 2048, 512) f32
  const float* h0 = (const float*)d_in[1];    // (32, 512) f32
  const float* Wx = (const float*)d_in[2];    // (512, 2048) f32
  const float* Wh = (const float*)d_in[3];    // (512, 2048) f32
  const float* bias = (const float*)d_in[4];  // (2048,) f32
  float* out = (float*)d_out;

  char* ws = (char*)d_ws;
  unsigned short* wxp = (unsigned short*)(ws);                            // 2 MB
  unsigned short* whp = (unsigned short*)(ws + (2u << 20));               // 2 MB
  unsigned short* hbuf = (unsigned short*)(ws + (4u << 20));              // 128 KB
  unsigned short* xb = (unsigned short*)(ws + (8u << 20));                // 64 MB

  hipLaunchKernelGGL(prep_kernel, dim3(8224), dim3(256), 0, stream,
                     Wx, Wh, h0, wxp, whp, hbuf);
  hipLaunchKernelGGL(xprep_kernel, dim3(16384), dim3(256), 0, stream, x, xb);
  hipLaunchKernelGGL(scan_kernel, dim3(NWG), dim3(256), 0, stream,
                     xb, bias, wxp, whp, hbuf, out);
}

// Round 5
// 10515.779 us; speedup vs baseline: 3.3202x; 1.3340x over previous
//
#include <hip/hip_runtime.h>

typedef __attribute__((ext_vector_type(8))) short short8;       // bf16x8 MFMA frag
typedef __attribute__((ext_vector_type(8))) unsigned short ushort8;
typedef __attribute__((ext_vector_type(4))) float f32x4;
typedef __attribute__((ext_vector_type(4))) int i32x4;

#define T_STEPS 2048
#define NWG 32

static __device__ __forceinline__ unsigned short f2bf(float f) {
  unsigned u = __builtin_bit_cast(unsigned, f);
  unsigned r = u + 0x7fffu + ((u >> 16) & 1u);   // RNE
  return (unsigned short)(r >> 16);
}
static __device__ __forceinline__ float bf2f(unsigned short h) {
  unsigned u = ((unsigned)h) << 16;
  return __builtin_bit_cast(float, u);
}
static __device__ __forceinline__ float fast_sigmoid(float v) {
  return __builtin_amdgcn_rcpf(1.0f + __expf(-v));
}
static __device__ __forceinline__ float fast_tanh(float v) {
  // tanh(x) = 1 - 2/(e^{2x}+1); saturates correctly at both ends
  return 1.0f - 2.0f * __builtin_amdgcn_rcpf(1.0f + __expf(2.0f * v));
}

// Pack layout for W (both Wx and Wh, each (512 x 2048) row-major):
// p[s][g][kt][l][e] : s<32 (slice), g<4 (gate), kt<16 (K-tile), l<64, e<8
// element = W[k][c] with k = kt*32 + (l>>4)*8 + e ; c = g*512 + s*16 + (l&15)
//
// h exchange: hbuf[slot][plane][32*512] bf16, slot = t&1 holds h_t. Every
// ushort carries tag=(t>>1)&3 in its 2 mantissa LSBs (hi steal absorbed by
// lo = h - bf2f(hi_forced); lo steal ~2^-14|h|). Data is self-validating:
// any granularity, any cache staleness -> tag mismatch -> retry. Skew proof:
// a WG publishes h_{t+1} only after all 4 waves (union = all 32 producers)
// validated h_t, so max skew < 2 steps; ring alias t vs t-2 differs by 1 mod 4;
// replay leftovers (tag 3/0) and 0xAA poison (tag 2) never match first reads.
__global__ void prep_kernel(const float* __restrict__ Wx, const float* __restrict__ Wh,
                            const float* __restrict__ h0,
                            unsigned short* __restrict__ wxp, unsigned short* __restrict__ whp,
                            unsigned short* __restrict__ hbuf, int* __restrict__ ctl) {
  int idx = blockIdx.x * 256 + threadIdx.x;
  if (idx < 2097152) {
    int which = idx >> 20;
    int r = idx & 1048575;
    int e = r & 7;
    int l = (r >> 3) & 63;
    int kt = (r >> 9) & 15;
    int g = (r >> 13) & 3;
    int s = r >> 15;
    int k = kt * 32 + ((l >> 4) << 3) + e;
    int c = g * 512 + s * 16 + (l & 15);
    const float* W = which ? Wh : Wx;
    unsigned short* dst = which ? whp : wxp;
    dst[r] = f2bf(W[k * 2048 + c]);
  } else if (idx < 2105344) {
    int r2 = (idx - 2097152) * 2;          // pair of (b*512+k)
    float v0 = h0[r2], v1 = h0[r2 + 1];
    // tag(step 0) = 0 : force 2 LSBs of hi and lo to 0
    unsigned short hi0 = f2bf(v0) & 0xFFFCu, hi1 = f2bf(v1) & 0xFFFCu;
    unsigned short lo0 = f2bf(v0 - bf2f(hi0)) & 0xFFFCu;
    unsigned short lo1 = f2bf(v1 - bf2f(hi1)) & 0xFFFCu;
    // slot 0 (input of step 0): hi plane at 0, lo plane at 16384 (MALL-visible)
    __hip_atomic_store((unsigned*)&hbuf[r2], (unsigned)hi0 | ((unsigned)hi1 << 16),
                       __ATOMIC_RELAXED, __HIP_MEMORY_SCOPE_AGENT);
    __hip_atomic_store((unsigned*)&hbuf[16384 + r2], (unsigned)lo0 | ((unsigned)lo1 << 16),
                       __ATOMIC_RELAXED, __HIP_MEMORY_SCOPE_AGENT);
  } else {
    int j = idx - 2105344;
    // ctl[0..7] per-XCD tickets, ctl[8] winner (-1 / xcc / 100=mixed), ctl[9] mixed tickets
    if (j < 10)
      __hip_atomic_store(&ctl[j], (j == 8) ? -1 : 0,
                         __ATOMIC_RELAXED, __HIP_MEMORY_SCOPE_AGENT);
  }
}

// Transpose x (b,t,d) f32 -> xt (t,b,d) bf16 (one contiguous 32 KB block/step).
__global__ void xprep_kernel(const float* __restrict__ x, unsigned short* __restrict__ xb) {
  size_t i8 = ((size_t)blockIdx.x * 256 + threadIdx.x) * 8;
  int t = (int)(i8 >> 14);
  int r = (int)(i8 & 16383);
  int b = r >> 9;
  int d = r & 511;
  const float* src = x + ((size_t)b * 2048 + (size_t)t) * 512 + d;
  f32x4 a = *(const f32x4*)src;
  f32x4 c = *(const f32x4*)(src + 4);
  ushort8 o;
#pragma unroll
  for (int e = 0; e < 4; ++e) {
    o[e] = f2bf(a[e]);
    o[e + 4] = f2bf(c[e]);
  }
  *(ushort8*)(xb + i8) = o;
}

// 256 WGs (1/CU via 145KB LDS). Fast mode: the 32 WGs of one XCD win; h moves
// through that XCD's write-through-L1 -> shared-L2 path with PLAIN loads/stores,
// correctness guarded by tags (stale L1 lines are capacity-evicted: each sweep
// pushes 64KB/CU through the 32KB L1). Mixed fallback: round-3 agent atomics.
__global__ __launch_bounds__(256, 1) void scan_kernel(
    const unsigned short* __restrict__ xb, const float* __restrict__ bias,
    const unsigned short* __restrict__ wxp, const unsigned short* __restrict__ whp,
    unsigned short* __restrict__ hbuf, float* __restrict__ out, int* __restrict__ ctl) {
  __shared__ unsigned short WxL[4][16][512];   // 64 KB  [g][ktglob][l*8+e]
  __shared__ unsigned short WhL[4][16][512];   // 64 KB
  __shared__ float gA[32][68];                 // 8.5 KB partial sums (padded)
  __shared__ float gB[32][68];                 // 8.5 KB
  __shared__ int s_slice, s_fast;

  const int tid = threadIdx.x;
  const int lane = tid & 63;
  const int gw = tid >> 6;                     // wave id == K-slice id

  // ---- XCD claim with timeout fallback (always terminates)
  if (tid == 0) {
    unsigned xcc;
    asm volatile("s_getreg_b32 %0, hwreg(HW_REG_XCC_ID)" : "=s"(xcc));
    xcc &= 7;
    int tk = __hip_atomic_fetch_add(&ctl[xcc], 1, __ATOMIC_RELAXED,
                                    __HIP_MEMORY_SCOPE_AGENT);
    int my = -1, fm = 1;
    if (tk < NWG) {
      if (tk == NWG - 1) {
        int e = -1;
        __hip_atomic_compare_exchange_strong(&ctl[8], &e, (int)xcc,
                                             __ATOMIC_RELAXED, __ATOMIC_RELAXED,
                                             __HIP_MEMORY_SCOPE_AGENT);
      }
      int w = -1;
      for (int sp = 0;; ++sp) {
        w = __hip_atomic_load(&ctl[8], __ATOMIC_RELAXED, __HIP_MEMORY_SCOPE_AGENT);
        if (w != -1) break;
        if (sp > 30000) {                       // ~ms-scale: no XCD filled -> mixed
          int e = -1;
          __hip_atomic_compare_exchange_strong(&ctl[8], &e, 100,
                                               __ATOMIC_RELAXED, __ATOMIC_RELAXED,
                                               __HIP_MEMORY_SCOPE_AGENT);
          w = __hip_atomic_load(&ctl[8], __ATOMIC_RELAXED, __HIP_MEMORY_SCOPE_AGENT);
          break;
        }
        __builtin_amdgcn_s_sleep(2);
      }
      if (w == (int)xcc) {
        my = tk;                                // fast: same-XCD crew
      } else if (w >= 100) {
        int mt = __hip_atomic_fetch_add(&ctl[9], 1, __ATOMIC_RELAXED,
                                        __HIP_MEMORY_SCOPE_AGENT);
        if (mt < NWG) { my = mt; fm = 0; }      // mixed: MALL protocol
      }
    }
    s_slice = my;
    s_fast = fm;
  }
  __syncthreads();
  const int s = s_slice;
  const int fast = s_fast;
  if (s < 0) return;

  // ---- stage packed W slices into LDS
  {
    const ushort8* sx = (const ushort8*)(wxp + (size_t)s * 32768);
    const ushort8* sh = (const ushort8*)(whp + (size_t)s * 32768);
    ushort8* dx = (ushort8*)&WxL[0][0][0];
    ushort8* dh = (ushort8*)&WhL[0][0][0];
    for (int i = tid; i < 4096; i += 256) {
      dx[i] = sx[i];
      dh[i] = sh[i];
    }
  }

  const int p0 = tid * 2;
  const int ob = p0 >> 4;        // batch 0..31
  const int oj = p0 & 15;        // even unit index
  float2 bias2[4];
#pragma unroll
  for (int g = 0; g < 4; ++g)
    bias2[g] = *(const float2*)&bias[g * 512 + s * 16 + oj];

  float c0 = 0.f, c1 = 0.f;
  const int arow = lane & 15;
  const int kgrp = (lane >> 4) * 8;

  __syncthreads();

  // prologue: prefetch x A-frags for t=0 (plain cached loads)
  short8 xf0[4], xf1[4];
#pragma unroll
  for (int kt = 0; kt < 4; ++kt) {
    const int k0 = (gw << 7) + (kt << 5) + kgrp;
    xf0[kt] = *(const short8*)&xb[arow * 512 + k0];
    xf1[kt] = *(const short8*)&xb[(arow + 16) * 512 + k0];
  }

  for (int t = 0; t < T_STEPS; ++t) {
    // ---- phase 1: tagged poll; the polls ARE the data loads
    const unsigned tp = 0x00010001u * (unsigned)((t >> 1) & 3);
    const unsigned short* hrd = hbuf + (t & 1) * 32768;
    i32x4 q[16];
    if (fast) {
      for (;;) {
#pragma unroll
        for (int kt = 0; kt < 4; ++kt) {
          const int k0 = (gw << 7) + (kt << 5) + kgrp;
          const unsigned short* pa = hrd + arow * 512 + k0;
          const unsigned short* pb = hrd + 16384 + arow * 512 + k0;
          const unsigned short* pc = hrd + (arow + 16) * 512 + k0;
          const unsigned short* pd = hrd + 16384 + (arow + 16) * 512 + k0;
          asm volatile("global_load_dwordx4 %0, %1, off" : "=v"(q[kt * 4 + 0]) : "v"(pa));
          asm volatile("global_load_dwordx4 %0, %1, off" : "=v"(q[kt * 4 + 1]) : "v"(pb));
          asm volatile("global_load_dwordx4 %0, %1, off" : "=v"(q[kt * 4 + 2]) : "v"(pc));
          asm volatile("global_load_dwordx4 %0, %1, off" : "=v"(q[kt * 4 + 3]) : "v"(pd));
        }
        asm volatile("s_waitcnt vmcnt(0)" ::: "memory");
        __builtin_amdgcn_sched_barrier(0);
        unsigned bad = 0;
#pragma unroll
        for (int i = 0; i < 16; ++i)
#pragma unroll
          for (int j = 0; j < 4; ++j)
            bad |= (((unsigned)q[i][j]) & 0x00030003u) ^ tp;
        if (__all(bad == 0)) break;
      }
    } else {
      const unsigned long long* hb64 = (const unsigned long long*)hrd;
      for (;;) {
#pragma unroll
        for (int kt = 0; kt < 4; ++kt) {
          const int k0 = (gw << 7) + (kt << 5) + kgrp;
          const int base[4] = {(arow * 512 + k0) >> 2, (16384 + arow * 512 + k0) >> 2,
                               ((arow + 16) * 512 + k0) >> 2,
                               (16384 + (arow + 16) * 512 + k0) >> 2};
#pragma unroll
          for (int m = 0; m < 4; ++m) {
            union { unsigned long long u[2]; i32x4 v; } uu;
            uu.u[0] = __hip_atomic_load(hb64 + base[m], __ATOMIC_RELAXED,
                                        __HIP_MEMORY_SCOPE_AGENT);
            uu.u[1] = __hip_atomic_load(hb64 + base[m] + 1, __ATOMIC_RELAXED,
                                        __HIP_MEMORY_SCOPE_AGENT);
            q[kt * 4 + m] = uu.v;
          }
        }
        unsigned bad = 0;
#pragma unroll
        for (int i = 0; i < 16; ++i)
#pragma unroll
          for (int j = 0; j < 4; ++j)
            bad |= (((unsigned)q[i][j]) & 0x00030003u) ^ tp;
        if (__all(bad == 0)) break;
      }
    }

    // ---- phase 2: MFMA
    f32x4 acc[4][2];
#pragma unroll
    for (int nt = 0; nt < 4; ++nt)
#pragma unroll
      for (int mt = 0; mt < 2; ++mt)
        acc[nt][mt] = (f32x4){0.f, 0.f, 0.f, 0.f};

#pragma unroll
    for (int kt = 0; kt < 4; ++kt) {
      const int ktg = (gw << 2) + kt;
      short8 hh0 = __builtin_bit_cast(short8, q[kt * 4 + 0]);
      short8 hl0 = __builtin_bit_cast(short8, q[kt * 4 + 1]);
      short8 hh1 = __builtin_bit_cast(short8, q[kt * 4 + 2]);
      short8 hl1 = __builtin_bit_cast(short8, q[kt * 4 + 3]);
#pragma unroll
      for (int nt = 0; nt < 4; ++nt) {
        short8 bx = *(const short8*)&WxL[nt][ktg][lane * 8];
        short8 bh = *(const short8*)&WhL[nt][ktg][lane * 8];
        acc[nt][0] = __builtin_amdgcn_mfma_f32_16x16x32_bf16(xf0[kt], bx, acc[nt][0], 0, 0, 0);
        acc[nt][0] = __builtin_amdgcn_mfma_f32_16x16x32_bf16(hh0, bh, acc[nt][0], 0, 0, 0);
        acc[nt][0] = __builtin_amdgcn_mfma_f32_16x16x32_bf16(hl0, bh, acc[nt][0], 0, 0, 0);
        acc[nt][1] = __builtin_amdgcn_mfma_f32_16x16x32_bf16(xf1[kt], bx, acc[nt][1], 0, 0, 0);
        acc[nt][1] = __builtin_amdgcn_mfma_f32_16x16x32_bf16(hh1, bh, acc[nt][1], 0, 0, 0);
        acc[nt][1] = __builtin_amdgcn_mfma_f32_16x16x32_bf16(hl1, bh, acc[nt][1], 0, 0, 0);
      }
    }

    // ---- phase 3: LDS partial-sum exchange (waves 2,3 store; 0,1 add)
    {
      float* dst = (gw & 1) ? &gB[0][0] : &gA[0][0];
      if (gw >= 2) {
#pragma unroll
        for (int nt = 0; nt < 4; ++nt)
#pragma unroll
          for (int mt = 0; mt < 2; ++mt)
#pragma unroll
            for (int r = 0; r < 4; ++r)
              dst[(mt * 16 + (lane >> 4) * 4 + r) * 68 + nt * 16 + (lane & 15)] =
                  acc[nt][mt][r];
      }
      __syncthreads();
      if (gw < 2) {
#pragma unroll
        for (int nt = 0; nt < 4; ++nt)
#pragma unroll
          for (int mt = 0; mt < 2; ++mt)
#pragma unroll
            for (int r = 0; r < 4; ++r)
              dst[(mt * 16 + (lane >> 4) * 4 + r) * 68 + nt * 16 + (lane & 15)] +=
                  acc[nt][mt][r];
      }
      __syncthreads();
    }

    // ---- phase 4: gates, c/h update (2 (batch,unit) pairs per thread)
    float2 v4[4];
#pragma unroll
    for (int g = 0; g < 4; ++g) {
      float2 a2 = *(float2*)&gA[ob][g * 16 + oj];
      float2 b2 = *(float2*)&gB[ob][g * 16 + oj];
      v4[g].x = a2.x + b2.x + bias2[g].x;
      v4[g].y = a2.y + b2.y + bias2[g].y;
    }
    float i0 = fast_sigmoid(v4[0].x), i1 = fast_sigmoid(v4[0].y);
    float f0 = fast_sigmoid(v4[1].x), f1 = fast_sigmoid(v4[1].y);
    float o0 = fast_sigmoid(v4[2].x), o1 = fast_sigmoid(v4[2].y);
    float g0 = fast_tanh(v4[3].x), g1 = fast_tanh(v4[3].y);
    c0 = f0 * c0 + i0 * g0;
    c1 = f1 * c1 + i1 * g1;
    float hv0 = o0 * fast_tanh(c0);
    float hv1 = o1 * fast_tanh(c1);

    // ---- phase 5: publish tagged h (fire-and-forget; write-through reaches L2)
    const unsigned ntag = (unsigned)(((t + 1) >> 1) & 3);
    unsigned short hi0 = (unsigned short)((f2bf(hv0) & 0xFFFCu) | ntag);
    unsigned short hi1 = (unsigned short)((f2bf(hv1) & 0xFFFCu) | ntag);
    unsigned short lo0 = (unsigned short)((f2bf(hv0 - bf2f(hi0)) & 0xFFFCu) | ntag);
    unsigned short lo1 = (unsigned short)((f2bf(hv1 - bf2f(hi1)) & 0xFFFCu) | ntag);
    unsigned short* hwr = hbuf + ((t + 1) & 1) * 32768;
    const int hidx = ob * 512 + s * 16 + oj;
    unsigned whi = (unsigned)hi0 | ((unsigned)hi1 << 16);
    unsigned wlo = (unsigned)lo0 | ((unsigned)lo1 << 16);
    if (fast) {
      unsigned* pw1 = (unsigned*)&hwr[hidx];
      unsigned* pw2 = (unsigned*)&hwr[16384 + hidx];
      asm volatile("global_store_dword %0, %1, off" :: "v"(pw1), "v"(whi) : "memory");
      asm volatile("global_store_dword %0, %1, off" :: "v"(pw2), "v"(wlo) : "memory");
    } else {
      __hip_atomic_store((unsigned*)&hwr[hidx], whi, __ATOMIC_RELAXED,
                         __HIP_MEMORY_SCOPE_AGENT);
      __hip_atomic_store((unsigned*)&hwr[16384 + hidx], wlo, __ATOMIC_RELAXED,
                         __HIP_MEMORY_SCOPE_AGENT);
    }

    // gbuf WAR guard (only 2 dword stores in flight -> cheap vmcnt drain)
    __syncthreads();

    // ---- phase 6 (floats into next poll): out store + next x prefetch
    float2 hv2 = {hv0, hv1};
    *(float2*)&out[(size_t)ob * (2048 * 512) + (size_t)t * 512 + s * 16 + oj] = hv2;
    {
      const int tn = (t + 1 < T_STEPS) ? (t + 1) : t;
      const unsigned short* xt1 = xb + (size_t)tn * 16384;
#pragma unroll
      for (int kt = 0; kt < 4; ++kt) {
        const int k0 = (gw << 7) + (kt << 5) + kgrp;
        xf0[kt] = *(const short8*)&xt1[arow * 512 + k0];
        xf1[kt] = *(const short8*)&xt1[(arow + 16) * 512 + k0];
      }
    }
  }
}

extern "C" void kernel_launch(void* const* d_in, const int* in_sizes, int n_in,
                              void* d_out, int out_size, void* d_ws, size_t ws_size,
                              hipStream_t stream) {
  const float* x = (const float*)d_in[0];     // (32, 2048, 512) f32
  const float* h0 = (const float*)d_in[1];    // (32, 512) f32
  const float* Wx = (const float*)d_in[2];    // (512, 2048) f32
  const float* Wh = (const float*)d_in[3];    // (512, 2048) f32
  const float* bias = (const float*)d_in[4];  // (2048,) f32
  float* out = (float*)d_out;

  char* ws = (char*)d_ws;
  unsigned short* wxp = (unsigned short*)(ws);                            // 2 MB
  unsigned short* whp = (unsigned short*)(ws + (2u << 20));               // 2 MB
  unsigned short* hbuf = (unsigned short*)(ws + (4u << 20));              // 128 KB
  int* ctl = (int*)(ws + (4u << 20) + (256u << 10));                      // 40 B
  unsigned short* xb = (unsigned short*)(ws + (8u << 20));                // 64 MB

  hipLaunchKernelGGL(prep_kernel, dim3(8225), dim3(256), 0, stream,
                     Wx, Wh, h0, wxp, whp, hbuf, ctl);
  hipLaunchKernelGGL(xprep_kernel, dim3(16384), dim3(256), 0, stream, x, xb);
  hipLaunchKernelGGL(scan_kernel, dim3(256), dim3(256), 0, stream,
                     xb, bias, wxp, whp, hbuf, out, ctl);
}